// Round 1
// baseline (573.207 us; speedup 1.0000x reference)
//
#include <hip/hip_runtime.h>

#define D 128
#define GEMM_ROWS 64

// ---------------- degree: cnt[dst] += 1 per edge ----------------
__global__ __launch_bounds__(256) void deg_kernel(const int* __restrict__ ei_dst,
                                                  unsigned int* __restrict__ cnt, int E) {
    int e = blockIdx.x * 256 + threadIdx.x;
    if (e < E) atomicAdd(&cnt[ei_dst[e]], 1u);
}

// ---------------- dis[i] = rsqrt(deg) with self-loop (+1) ----------------
__global__ __launch_bounds__(256) void dis_kernel(const unsigned int* __restrict__ cnt,
                                                  float* __restrict__ dis, int n) {
    int i = blockIdx.x * 256 + threadIdx.x;
    if (i < n) dis[i] = rsqrtf((float)cnt[i] + 1.0f);
}

// ---------------- h = X*W ; out = h*dis^2 + b (self-loop fused) ----------------
// W (128x128 f32 = 64KB) staged in LDS; 64-row X tile (32KB) in LDS.
// 512 threads: thread (g=tid/32, l=tid%32) computes rows g*4..+3, cols l*4..+3.
__global__ __launch_bounds__(512) void gemm_kernel(const float* __restrict__ x,
                                                   const float* __restrict__ W,
                                                   const float* __restrict__ b,
                                                   const float* __restrict__ dis,
                                                   float* __restrict__ h,
                                                   float* __restrict__ out, int n) {
    __shared__ float Ws[D * D];
    __shared__ float xs[GEMM_ROWS * D];
    int tid = threadIdx.x;

    const float4* W4 = (const float4*)W;
    float4* Ws4 = (float4*)Ws;
#pragma unroll
    for (int i = 0; i < 8; ++i) Ws4[tid + i * 512] = W4[tid + i * 512];

    int rowbase = blockIdx.x * GEMM_ROWS;
    int nrows = min(GEMM_ROWS, n - rowbase);
    const float4* x4 = (const float4*)(x + (size_t)rowbase * D);
    float4* xs4 = (float4*)xs;
    for (int i = tid; i < nrows * 32; i += 512) xs4[i] = x4[i];
    __syncthreads();

    int g = tid >> 5, l = tid & 31;
    int c0 = l * 4, r0 = g * 4;
    float acc[4][4] = {};
#pragma unroll 4
    for (int k = 0; k < D; ++k) {
        float4 w = *(const float4*)&Ws[k * D + c0];
#pragma unroll
        for (int rr = 0; rr < 4; ++rr) {
            float xv = xs[(r0 + rr) * D + k];
            acc[rr][0] += xv * w.x;
            acc[rr][1] += xv * w.y;
            acc[rr][2] += xv * w.z;
            acc[rr][3] += xv * w.w;
        }
    }

    float4 bv = *(const float4*)&b[c0];
#pragma unroll
    for (int rr = 0; rr < 4; ++rr) {
        int r = r0 + rr;
        if (r < nrows) {
            size_t off = (size_t)(rowbase + r) * D + c0;
            float4 hv = make_float4(acc[rr][0], acc[rr][1], acc[rr][2], acc[rr][3]);
            *(float4*)&h[off] = hv;
            float dv = dis[rowbase + r];
            float s = dv * dv;  // self-loop norm = 1/deg
            *(float4*)&out[off] =
                make_float4(hv.x * s + bv.x, hv.y * s + bv.y, hv.z * s + bv.z, hv.w * s + bv.w);
        }
    }
}

// ---------------- edge scatter: out[dst] += h[src] * dis[src]*dis[dst] ----------------
// One wave (64 lanes) per edge, 2 floats/lane; grid-stride over edges.
__global__ __launch_bounds__(256) void scatter_kernel(const int* __restrict__ ei,
                                                      const float* __restrict__ dis,
                                                      const float* __restrict__ h,
                                                      float* __restrict__ out, int E) {
    int lane = threadIdx.x & 63;
    int wave = (blockIdx.x * blockDim.x + threadIdx.x) >> 6;
    int nwaves = (gridDim.x * blockDim.x) >> 6;
    for (int e = wave; e < E; e += nwaves) {
        int src = ei[e];
        int dst = ei[E + e];
        float w = dis[src] * dis[dst];
        float2 hv = ((const float2*)(h + (size_t)src * D))[lane];
        float* op = out + (size_t)dst * D + lane * 2;
        atomicAdd(op, hv.x * w);
        atomicAdd(op + 1, hv.y * w);
    }
}

extern "C" void kernel_launch(void* const* d_in, const int* in_sizes, int n_in,
                              void* d_out, int out_size, void* d_ws, size_t ws_size,
                              hipStream_t stream) {
    const float* x = (const float*)d_in[0];
    const int* ei = (const int*)d_in[1];   // [2, E] int32
    const float* W = (const float*)d_in[2];
    const float* b = (const float*)d_in[3];
    float* out = (float*)d_out;

    int n = in_sizes[0] / D;  // 50000
    int E = in_sizes[1] / 2;  // 600000

    unsigned int* cnt = (unsigned int*)d_ws;
    float* dis = (float*)d_ws + n;
    float* h = (float*)d_ws + 2 * (size_t)n;  // byte offset 400000, 16B-aligned

    hipMemsetAsync(cnt, 0, n * sizeof(unsigned int), stream);
    deg_kernel<<<(E + 255) / 256, 256, 0, stream>>>(ei + E, cnt, E);
    dis_kernel<<<(n + 255) / 256, 256, 0, stream>>>(cnt, dis, n);
    gemm_kernel<<<(n + GEMM_ROWS - 1) / GEMM_ROWS, 512, 0, stream>>>(x, W, b, dis, h, out, n);
    scatter_kernel<<<2048, 256, 0, stream>>>(ei, dis, h, out, E);
}

// Round 2
// 269.842 us; speedup vs baseline: 2.1242x; 2.1242x over previous
//
#include <hip/hip_runtime.h>

#define D 128
#define GEMM_ROWS 64

// ---------------- degree: cnt[dst] += 1 per edge ----------------
__global__ __launch_bounds__(256) void deg_kernel(const int* __restrict__ ei_dst,
                                                  unsigned int* __restrict__ cnt, int E) {
    int e = blockIdx.x * 256 + threadIdx.x;
    if (e < E) atomicAdd(&cnt[ei_dst[e]], 1u);
}

// ---------------- exclusive scan of cnt -> off, cursor (single block) ----------------
__global__ __launch_bounds__(1024) void scan_kernel(const unsigned int* __restrict__ cnt,
                                                    unsigned int* __restrict__ off,
                                                    unsigned int* __restrict__ cursor, int n) {
    __shared__ unsigned int sums[1024];
    int t = threadIdx.x;
    int chunk = (n + 1023) / 1024;
    int s = t * chunk, e = min(s + chunk, n);
    unsigned int local = 0;
    for (int i = s; i < e; ++i) local += cnt[i];
    sums[t] = local;
    __syncthreads();
    for (int d = 1; d < 1024; d <<= 1) {
        unsigned int v = (t >= d) ? sums[t - d] : 0u;
        __syncthreads();
        sums[t] += v;
        __syncthreads();
    }
    unsigned int base = (t > 0) ? sums[t - 1] : 0u;
    for (int i = s; i < e; ++i) {
        off[i] = base;
        cursor[i] = base;
        base += cnt[i];
    }
}

// ---------------- dis[i] = rsqrt(deg+1) ----------------
__global__ __launch_bounds__(256) void dis_kernel(const unsigned int* __restrict__ cnt,
                                                  float* __restrict__ dis, int n) {
    int i = blockIdx.x * 256 + threadIdx.x;
    if (i < n) dis[i] = rsqrtf((float)cnt[i] + 1.0f);
}

// ---------------- place edges into dst-sorted order ----------------
__global__ __launch_bounds__(256) void place_kernel(const int* __restrict__ ei,
                                                    unsigned int* __restrict__ cursor,
                                                    int* __restrict__ sorted_src, int E) {
    int e = blockIdx.x * 256 + threadIdx.x;
    if (e < E) {
        int src = ei[e];
        int dst = ei[E + e];
        unsigned int p = atomicAdd(&cursor[dst], 1u);
        sorted_src[p] = src;
    }
}

// ---------------- hs = (X*W) * dis[row] ----------------
// W (64KB) in LDS; 64-row X tile (32KB) in LDS. 512 threads, 4x4 per thread.
__global__ __launch_bounds__(512) void gemm_kernel(const float* __restrict__ x,
                                                   const float* __restrict__ W,
                                                   const float* __restrict__ dis,
                                                   float* __restrict__ hs, int n) {
    __shared__ float Ws[D * D];
    __shared__ float xs[GEMM_ROWS * D];
    int tid = threadIdx.x;

    const float4* W4 = (const float4*)W;
    float4* Ws4 = (float4*)Ws;
#pragma unroll
    for (int i = 0; i < 8; ++i) Ws4[tid + i * 512] = W4[tid + i * 512];

    int rowbase = blockIdx.x * GEMM_ROWS;
    int nrows = min(GEMM_ROWS, n - rowbase);
    const float4* x4 = (const float4*)(x + (size_t)rowbase * D);
    float4* xs4 = (float4*)xs;
    for (int i = tid; i < nrows * 32; i += 512) xs4[i] = x4[i];
    __syncthreads();

    int g = tid >> 5, l = tid & 31;
    int c0 = l * 4, r0 = g * 4;
    float acc[4][4] = {};
#pragma unroll 4
    for (int k = 0; k < D; ++k) {
        float4 w = *(const float4*)&Ws[k * D + c0];
#pragma unroll
        for (int rr = 0; rr < 4; ++rr) {
            float xv = xs[(r0 + rr) * D + k];
            acc[rr][0] += xv * w.x;
            acc[rr][1] += xv * w.y;
            acc[rr][2] += xv * w.z;
            acc[rr][3] += xv * w.w;
        }
    }

#pragma unroll
    for (int rr = 0; rr < 4; ++rr) {
        int r = r0 + rr;
        if (r < nrows) {
            float dv = dis[rowbase + r];
            size_t off = (size_t)(rowbase + r) * D + c0;
            *(float4*)&hs[off] = make_float4(acc[rr][0] * dv, acc[rr][1] * dv,
                                             acc[rr][2] * dv, acc[rr][3] * dv);
        }
    }
}

// ---------------- gather: out[dst] = dis[dst]*(hs[dst] + sum hs[src]) + b ----------------
// One wave per dst node; lane holds float2 (cols lane*2, lane*2+1).
__global__ __launch_bounds__(256) void gather_kernel(const int* __restrict__ sorted_src,
                                                     const unsigned int* __restrict__ off,
                                                     const unsigned int* __restrict__ cnt,
                                                     const float* __restrict__ dis,
                                                     const float* __restrict__ hs,
                                                     const float* __restrict__ b,
                                                     float* __restrict__ out, int n) {
    int wave = (blockIdx.x * 256 + threadIdx.x) >> 6;
    int lane = threadIdx.x & 63;
    if (wave >= n) return;
    int dst = wave;
    unsigned int s = off[dst];
    unsigned int c = cnt[dst];

    // self-loop term
    float2 acc = ((const float2*)(hs + (size_t)dst * D))[lane];

    for (unsigned int base = 0; base < c; base += 64) {
        int m = min(64u, c - base);
        int v = (base + (unsigned)lane < c) ? sorted_src[s + base + lane] : 0;
        for (int j = 0; j < m; ++j) {
            int src = __shfl(v, j);
            float2 hv = ((const float2*)(hs + (size_t)src * D))[lane];
            acc.x += hv.x;
            acc.y += hv.y;
        }
    }

    float dd = dis[dst];
    float2 bv = ((const float2*)b)[lane];
    float2 o;
    o.x = acc.x * dd + bv.x;
    o.y = acc.y * dd + bv.y;
    ((float2*)(out + (size_t)dst * D))[lane] = o;
}

extern "C" void kernel_launch(void* const* d_in, const int* in_sizes, int n_in,
                              void* d_out, int out_size, void* d_ws, size_t ws_size,
                              hipStream_t stream) {
    const float* x = (const float*)d_in[0];
    const int* ei = (const int*)d_in[1];  // [2, E] int32
    const float* W = (const float*)d_in[2];
    const float* b = (const float*)d_in[3];
    float* out = (float*)d_out;

    int n = in_sizes[0] / D;  // 50000
    int E = in_sizes[1] / 2;  // 600000

    unsigned int* cnt = (unsigned int*)d_ws;
    unsigned int* off = cnt + n;
    unsigned int* cursor = off + n;
    float* dis = (float*)(cursor + n);
    int* sorted_src = (int*)(dis + n);
    float* hs = (float*)(sorted_src + E);

    hipMemsetAsync(cnt, 0, n * sizeof(unsigned int), stream);
    deg_kernel<<<(E + 255) / 256, 256, 0, stream>>>(ei + E, cnt, E);
    scan_kernel<<<1, 1024, 0, stream>>>(cnt, off, cursor, n);
    dis_kernel<<<(n + 255) / 256, 256, 0, stream>>>(cnt, dis, n);
    place_kernel<<<(E + 255) / 256, 256, 0, stream>>>(ei, cursor, sorted_src, E);
    gemm_kernel<<<(n + GEMM_ROWS - 1) / GEMM_ROWS, 512, 0, stream>>>(x, W, dis, hs, n);
    gather_kernel<<<(n * 64 + 255) / 256, 256, 0, stream>>>(sorted_src, off, cnt, dis, hs, b,
                                                            out, n);
}

// Round 3
// 167.550 us; speedup vs baseline: 3.4211x; 1.6105x over previous
//
#include <hip/hip_runtime.h>

#define D 128
#define GEMM_ROWS 64
#define SCAN_CHUNK 1024  // elems per scan block (256 thr x 4)

// ---------------- degree: cnt[dst] += 1 per edge ----------------
__global__ __launch_bounds__(256) void deg_kernel(const int* __restrict__ ei_dst,
                                                  unsigned int* __restrict__ cnt, int E) {
    int e = blockIdx.x * 256 + threadIdx.x;
    if (e < E) atomicAdd(&cnt[ei_dst[e]], 1u);
}

// ---------------- scan phase 1: per-block reduce ----------------
__global__ __launch_bounds__(256) void reduce_kernel(const unsigned int* __restrict__ cnt,
                                                     unsigned int* __restrict__ bsum, int n) {
    int t = threadIdx.x;
    int i0 = blockIdx.x * SCAN_CHUNK + t * 4;
    unsigned int s = 0;
    if (i0 + 3 < n) {
        uint4 v = *(const uint4*)&cnt[i0];
        s = v.x + v.y + v.z + v.w;
    } else {
        for (int i = i0; i < n && i < i0 + 4; ++i) s += cnt[i];
    }
#pragma unroll
    for (int d = 32; d; d >>= 1) s += __shfl_down(s, d);
    __shared__ unsigned int ws_[4];
    int wid = t >> 6, lane = t & 63;
    if (lane == 0) ws_[wid] = s;
    __syncthreads();
    if (t == 0) bsum[blockIdx.x] = ws_[0] + ws_[1] + ws_[2] + ws_[3];
}

// ---------------- scan phase 2: exclusive scan of block sums (<=64) ----------------
__global__ __launch_bounds__(64) void bscan_kernel(unsigned int* __restrict__ bsum, int nb) {
    int lane = threadIdx.x;
    unsigned int v = (lane < nb) ? bsum[lane] : 0u;
    unsigned int s = v;
#pragma unroll
    for (int d = 1; d < 64; d <<= 1) {
        unsigned int u = __shfl_up(s, d);
        if (lane >= d) s += u;
    }
    if (lane < nb) bsum[lane] = s - v;
}

// ---------------- scan phase 3: block-local exclusive scan + writeback ----------------
__global__ __launch_bounds__(256) void scanwrite_kernel(const unsigned int* __restrict__ cnt,
                                                        const unsigned int* __restrict__ bsum,
                                                        unsigned int* __restrict__ off,
                                                        unsigned int* __restrict__ cursor,
                                                        int n) {
    int t = threadIdx.x;
    int i0 = blockIdx.x * SCAN_CHUNK + t * 4;
    unsigned int v0 = 0, v1 = 0, v2 = 0, v3 = 0;
    if (i0 + 3 < n) {
        uint4 v = *(const uint4*)&cnt[i0];
        v0 = v.x; v1 = v.y; v2 = v.z; v3 = v.w;
    } else if (i0 < n) {
        v0 = cnt[i0];
        if (i0 + 1 < n) v1 = cnt[i0 + 1];
        if (i0 + 2 < n) v2 = cnt[i0 + 2];
    }
    unsigned int tot = v0 + v1 + v2 + v3;
    unsigned int s = tot;
    int lane = t & 63, wid = t >> 6;
#pragma unroll
    for (int d = 1; d < 64; d <<= 1) {
        unsigned int u = __shfl_up(s, d);
        if (lane >= d) s += u;
    }
    __shared__ unsigned int wsum[4];
    if (lane == 63) wsum[wid] = s;
    __syncthreads();
    unsigned int base = bsum[blockIdx.x];
    for (int w = 0; w < wid; ++w) base += wsum[w];
    unsigned int tb = base + s - tot;
    unsigned int o0 = tb, o1 = tb + v0, o2 = o1 + v1, o3 = o2 + v2;
    if (i0 + 3 < n) {
        *(uint4*)&off[i0] = make_uint4(o0, o1, o2, o3);
        *(uint4*)&cursor[i0] = make_uint4(o0, o1, o2, o3);
    } else if (i0 < n) {
        off[i0] = o0; cursor[i0] = o0;
        if (i0 + 1 < n) { off[i0 + 1] = o1; cursor[i0 + 1] = o1; }
        if (i0 + 2 < n) { off[i0 + 2] = o2; cursor[i0 + 2] = o2; }
    }
}

// ---------------- dis[i] = rsqrt(deg+1) ----------------
__global__ __launch_bounds__(256) void dis_kernel(const unsigned int* __restrict__ cnt,
                                                  float* __restrict__ dis, int n) {
    int i = blockIdx.x * 256 + threadIdx.x;
    if (i < n) dis[i] = rsqrtf((float)cnt[i] + 1.0f);
}

// ---------------- place edges into dst-sorted order ----------------
__global__ __launch_bounds__(256) void place_kernel(const int* __restrict__ ei,
                                                    unsigned int* __restrict__ cursor,
                                                    int* __restrict__ sorted_src, int E) {
    int e = blockIdx.x * 256 + threadIdx.x;
    if (e < E) {
        int src = ei[e];
        int dst = ei[E + e];
        unsigned int p = atomicAdd(&cursor[dst], 1u);
        sorted_src[p] = src;
    }
}

// ---------------- hs = (X*W) * dis[row] ----------------
__global__ __launch_bounds__(512) void gemm_kernel(const float* __restrict__ x,
                                                   const float* __restrict__ W,
                                                   const float* __restrict__ dis,
                                                   float* __restrict__ hs, int n) {
    __shared__ float Ws[D * D];
    __shared__ float xs[GEMM_ROWS * D];
    int tid = threadIdx.x;

    const float4* W4 = (const float4*)W;
    float4* Ws4 = (float4*)Ws;
#pragma unroll
    for (int i = 0; i < 8; ++i) Ws4[tid + i * 512] = W4[tid + i * 512];

    int rowbase = blockIdx.x * GEMM_ROWS;
    int nrows = min(GEMM_ROWS, n - rowbase);
    const float4* x4 = (const float4*)(x + (size_t)rowbase * D);
    float4* xs4 = (float4*)xs;
    for (int i = tid; i < nrows * 32; i += 512) xs4[i] = x4[i];
    __syncthreads();

    int g = tid >> 5, l = tid & 31;
    int c0 = l * 4, r0 = g * 4;
    float acc[4][4] = {};
#pragma unroll 4
    for (int k = 0; k < D; ++k) {
        float4 w = *(const float4*)&Ws[k * D + c0];
#pragma unroll
        for (int rr = 0; rr < 4; ++rr) {
            float xv = xs[(r0 + rr) * D + k];
            acc[rr][0] += xv * w.x;
            acc[rr][1] += xv * w.y;
            acc[rr][2] += xv * w.z;
            acc[rr][3] += xv * w.w;
        }
    }

#pragma unroll
    for (int rr = 0; rr < 4; ++rr) {
        int r = r0 + rr;
        if (r < nrows) {
            float dv = dis[rowbase + r];
            size_t off = (size_t)(rowbase + r) * D + c0;
            *(float4*)&hs[off] = make_float4(acc[rr][0] * dv, acc[rr][1] * dv,
                                             acc[rr][2] * dv, acc[rr][3] * dv);
        }
    }
}

// ---------------- gather: out[dst] = dis[dst]*(hs[dst] + sum hs[src]) + b ----------------
// One HALF-wave (32 lanes) per dst node; lane holds float4 (cols l*4..l*4+3).
__global__ __launch_bounds__(256) void gather_kernel(const int* __restrict__ sorted_src,
                                                     const unsigned int* __restrict__ off,
                                                     const unsigned int* __restrict__ cnt,
                                                     const float* __restrict__ dis,
                                                     const float* __restrict__ hs,
                                                     const float* __restrict__ b,
                                                     float* __restrict__ out, int n) {
    int node = (blockIdx.x * 256 + threadIdx.x) >> 5;
    int l = threadIdx.x & 31;
    if (node >= n) return;
    unsigned int s = off[node];
    unsigned int c = cnt[node];
    const float4* hs4 = (const float4*)hs;

    float4 acc = hs4[(size_t)node * 32 + l];  // self-loop term

    for (unsigned int base = 0; base < c; base += 32) {
        int m = min(32u, c - base);
        int v = (base + (unsigned)l < c) ? sorted_src[s + base + l] : 0;
        for (int j = 0; j < m; ++j) {
            int src = __shfl(v, j, 32);
            float4 hv = hs4[(size_t)src * 32 + l];
            acc.x += hv.x; acc.y += hv.y; acc.z += hv.z; acc.w += hv.w;
        }
    }

    float dd = dis[node];
    float4 bv = ((const float4*)b)[l];
    ((float4*)out)[(size_t)node * 32 + l] =
        make_float4(acc.x * dd + bv.x, acc.y * dd + bv.y, acc.z * dd + bv.z, acc.w * dd + bv.w);
}

extern "C" void kernel_launch(void* const* d_in, const int* in_sizes, int n_in,
                              void* d_out, int out_size, void* d_ws, size_t ws_size,
                              hipStream_t stream) {
    const float* x = (const float*)d_in[0];
    const int* ei = (const int*)d_in[1];  // [2, E] int32
    const float* W = (const float*)d_in[2];
    const float* b = (const float*)d_in[3];
    float* out = (float*)d_out;

    int n = in_sizes[0] / D;  // 50000
    int E = in_sizes[1] / 2;  // 600000
    int nb = (n + SCAN_CHUNK - 1) / SCAN_CHUNK;  // 49

    unsigned int* cnt = (unsigned int*)d_ws;
    unsigned int* off = cnt + n;
    unsigned int* cursor = off + n;
    float* dis = (float*)(cursor + n);
    unsigned int* bsum = (unsigned int*)(dis + n);
    int* sorted_src = (int*)(bsum + 64);
    float* hs = (float*)(sorted_src + E);

    hipMemsetAsync(cnt, 0, n * sizeof(unsigned int), stream);
    deg_kernel<<<(E + 255) / 256, 256, 0, stream>>>(ei + E, cnt, E);
    reduce_kernel<<<nb, 256, 0, stream>>>(cnt, bsum, n);
    bscan_kernel<<<1, 64, 0, stream>>>(bsum, nb);
    scanwrite_kernel<<<nb, 256, 0, stream>>>(cnt, bsum, off, cursor, n);
    dis_kernel<<<(n + 255) / 256, 256, 0, stream>>>(cnt, dis, n);
    place_kernel<<<(E + 255) / 256, 256, 0, stream>>>(ei, cursor, sorted_src, E);
    gemm_kernel<<<(n + GEMM_ROWS - 1) / GEMM_ROWS, 512, 0, stream>>>(x, W, dis, hs, n);
    gather_kernel<<<(n * 32 + 255) / 256, 256, 0, stream>>>(sorted_src, off, cnt, dis, hs, b,
                                                            out, n);
}

// Round 4
// 135.593 us; speedup vs baseline: 4.2274x; 1.2357x over previous
//
#include <hip/hip_runtime.h>

#define D 128
#define SCAN_CHUNK 1024

typedef __bf16 bf16x8 __attribute__((ext_vector_type(8)));
typedef float f32x4 __attribute__((ext_vector_type(4)));

static __device__ __forceinline__ unsigned short f2bf(float x) {
    unsigned int u = __builtin_bit_cast(unsigned int, x);
    unsigned int r = u + 0x7fffu + ((u >> 16) & 1u);
    return (unsigned short)(r >> 16);
}
static __device__ __forceinline__ float bitf(unsigned int u) {
    return __builtin_bit_cast(float, u);
}

// ---------------- cast X -> bf16 ----------------
__global__ __launch_bounds__(256) void cast_kernel(const float* __restrict__ x,
                                                   unsigned short* __restrict__ xb, int n4) {
    int i = blockIdx.x * 256 + threadIdx.x;
    int stride = gridDim.x * 256;
    for (; i < n4; i += stride) {
        float4 v = ((const float4*)x)[i];
        ushort4 o;
        o.x = f2bf(v.x); o.y = f2bf(v.y); o.z = f2bf(v.z); o.w = f2bf(v.w);
        ((ushort4*)xb)[i] = o;
    }
}

// ---------------- Wt[n][k] = bf16(W[k][n]) ----------------
__global__ __launch_bounds__(256) void wt_kernel(const float* __restrict__ W,
                                                 unsigned short* __restrict__ Wt) {
    int t = blockIdx.x * 256 + threadIdx.x;  // 16384 total
    int r = t >> 7, c = t & 127;
    Wt[c * 128 + r] = f2bf(W[t]);
}

// ---------------- degree ----------------
__global__ __launch_bounds__(256) void deg_kernel(const int* __restrict__ ei_dst,
                                                  unsigned int* __restrict__ cnt, int E) {
    int e = blockIdx.x * 256 + threadIdx.x;
    if (e < E) atomicAdd(&cnt[ei_dst[e]], 1u);
}

// ---------------- scan phase 1: per-block reduce ----------------
__global__ __launch_bounds__(256) void reduce_kernel(const unsigned int* __restrict__ cnt,
                                                     unsigned int* __restrict__ bsum, int n) {
    int t = threadIdx.x;
    int i0 = blockIdx.x * SCAN_CHUNK + t * 4;
    unsigned int s = 0;
    if (i0 + 3 < n) {
        uint4 v = *(const uint4*)&cnt[i0];
        s = v.x + v.y + v.z + v.w;
    } else {
        for (int i = i0; i < n && i < i0 + 4; ++i) s += cnt[i];
    }
#pragma unroll
    for (int d = 32; d; d >>= 1) s += __shfl_down(s, d);
    __shared__ unsigned int ws_[4];
    int wid = t >> 6, lane = t & 63;
    if (lane == 0) ws_[wid] = s;
    __syncthreads();
    if (t == 0) bsum[blockIdx.x] = ws_[0] + ws_[1] + ws_[2] + ws_[3];
}

// ---------------- scan phase 2 ----------------
__global__ __launch_bounds__(64) void bscan_kernel(unsigned int* __restrict__ bsum, int nb) {
    int lane = threadIdx.x;
    unsigned int v = (lane < nb) ? bsum[lane] : 0u;
    unsigned int s = v;
#pragma unroll
    for (int d = 1; d < 64; d <<= 1) {
        unsigned int u = __shfl_up(s, d);
        if (lane >= d) s += u;
    }
    if (lane < nb) bsum[lane] = s - v;
}

// ---------------- scan phase 3: writeback cursor (start offsets) + dis ----------------
__global__ __launch_bounds__(256) void scanwrite_kernel(const unsigned int* __restrict__ cnt,
                                                        const unsigned int* __restrict__ bsum,
                                                        unsigned int* __restrict__ cursor,
                                                        float* __restrict__ dis, int n) {
    int t = threadIdx.x;
    int i0 = blockIdx.x * SCAN_CHUNK + t * 4;
    unsigned int v0 = 0, v1 = 0, v2 = 0, v3 = 0;
    if (i0 + 3 < n) {
        uint4 v = *(const uint4*)&cnt[i0];
        v0 = v.x; v1 = v.y; v2 = v.z; v3 = v.w;
    } else if (i0 < n) {
        v0 = cnt[i0];
        if (i0 + 1 < n) v1 = cnt[i0 + 1];
        if (i0 + 2 < n) v2 = cnt[i0 + 2];
    }
    unsigned int tot = v0 + v1 + v2 + v3;
    unsigned int s = tot;
    int lane = t & 63, wid = t >> 6;
#pragma unroll
    for (int d = 1; d < 64; d <<= 1) {
        unsigned int u = __shfl_up(s, d);
        if (lane >= d) s += u;
    }
    __shared__ unsigned int wsum[4];
    if (lane == 63) wsum[wid] = s;
    __syncthreads();
    unsigned int base = bsum[blockIdx.x];
    for (int w = 0; w < wid; ++w) base += wsum[w];
    unsigned int tb = base + s - tot;
    unsigned int o0 = tb, o1 = tb + v0, o2 = o1 + v1, o3 = o2 + v2;
    if (i0 + 3 < n) {
        *(uint4*)&cursor[i0] = make_uint4(o0, o1, o2, o3);
        *(float4*)&dis[i0] = make_float4(rsqrtf((float)v0 + 1.0f), rsqrtf((float)v1 + 1.0f),
                                         rsqrtf((float)v2 + 1.0f), rsqrtf((float)v3 + 1.0f));
    } else if (i0 < n) {
        cursor[i0] = o0; dis[i0] = rsqrtf((float)v0 + 1.0f);
        if (i0 + 1 < n) { cursor[i0 + 1] = o1; dis[i0 + 1] = rsqrtf((float)v1 + 1.0f); }
        if (i0 + 2 < n) { cursor[i0 + 2] = o2; dis[i0 + 2] = rsqrtf((float)v2 + 1.0f); }
    }
}

// ---------------- place edges into dst-sorted order ----------------
__global__ __launch_bounds__(256) void place_kernel(const int* __restrict__ ei,
                                                    unsigned int* __restrict__ cursor,
                                                    int* __restrict__ sorted_src, int E) {
    int e = blockIdx.x * 256 + threadIdx.x;
    if (e < E) {
        int src = ei[e];
        int dst = ei[E + e];
        unsigned int p = atomicAdd(&cursor[dst], 1u);
        sorted_src[p] = src;
    }
}

// ---------------- MFMA gemm: hs = bf16((Xb*W) * dis[row]) ----------------
// 256 thr = 4 waves; 64 rows x 128 cols per block; 16x16x32 bf16 MFMA.
// LDS tiles swizzled in 16B slots: phys_slot = log_slot ^ (row & 7).
__global__ __launch_bounds__(256) void mfma_gemm(const unsigned short* __restrict__ xb,
                                                 const unsigned short* __restrict__ wt,
                                                 const float* __restrict__ dis,
                                                 unsigned short* __restrict__ hs, int n) {
    __shared__ uint4 Xs[64 * 16];   // 16 KB
    __shared__ uint4 Ws[128 * 16];  // 32 KB
    int t = threadIdx.x;
    int rowbase = blockIdx.x * 64;

    const uint4* wg = (const uint4*)wt;
#pragma unroll
    for (int j = 0; j < 8; ++j) {
        int gi = t + j * 256;
        int r = gi >> 4, s = gi & 15;
        Ws[r * 16 + (s ^ (r & 7))] = wg[gi];
    }
    const uint4* xg = (const uint4*)xb;
#pragma unroll
    for (int j = 0; j < 4; ++j) {
        int gi = t + j * 256;
        int r = gi >> 4, s = gi & 15;
        uint4 v = make_uint4(0u, 0u, 0u, 0u);
        if (rowbase + r < n) v = xg[(size_t)rowbase * 16 + gi];
        Xs[r * 16 + (s ^ (r & 7))] = v;
    }
    __syncthreads();

    int w = t >> 6, l = t & 63;
    int lr = l & 15, lg = l >> 4;
    f32x4 acc[4][2] = {};

#pragma unroll
    for (int kt = 0; kt < 4; ++kt) {
        int ks = kt * 4 + lg;
        bf16x8 bfr[2];
#pragma unroll
        for (int ct = 0; ct < 2; ++ct) {
            int nc = w * 32 + ct * 16 + lr;
            bfr[ct] = __builtin_bit_cast(bf16x8, Ws[nc * 16 + (ks ^ (nc & 7))]);
        }
#pragma unroll
        for (int mt = 0; mt < 4; ++mt) {
            int mr = mt * 16 + lr;
            bf16x8 afr = __builtin_bit_cast(bf16x8, Xs[mr * 16 + (ks ^ (mr & 7))]);
            acc[mt][0] = __builtin_amdgcn_mfma_f32_16x16x32_bf16(afr, bfr[0], acc[mt][0], 0, 0, 0);
            acc[mt][1] = __builtin_amdgcn_mfma_f32_16x16x32_bf16(afr, bfr[1], acc[mt][1], 0, 0, 0);
        }
    }

#pragma unroll
    for (int mt = 0; mt < 4; ++mt) {
        int row0 = rowbase + mt * 16 + lg * 4;
#pragma unroll
        for (int r = 0; r < 4; ++r) {
            int grow = row0 + r;
            if (grow < n) {
                float dv = dis[grow];
#pragma unroll
                for (int ct = 0; ct < 2; ++ct) {
                    int col = w * 32 + ct * 16 + lr;
                    hs[(size_t)grow * 128 + col] = f2bf(acc[mt][ct][r] * dv);
                }
            }
        }
    }
}

// ---------------- gather: out[dst] = dis[dst]*(hs[dst] + sum hs[src]) + b ----------------
// Half-wave (32 lanes) per node; lane holds 4 bf16 cols (uint2 load).
__global__ __launch_bounds__(256) void gather_kernel(const int* __restrict__ sorted_src,
                                                     const unsigned int* __restrict__ cur_end,
                                                     const unsigned int* __restrict__ cnt,
                                                     const float* __restrict__ dis,
                                                     const unsigned short* __restrict__ hs,
                                                     const float* __restrict__ b,
                                                     float* __restrict__ out, int n) {
    int node = (blockIdx.x * 256 + threadIdx.x) >> 5;
    int l = threadIdx.x & 31;
    if (node >= n) return;
    unsigned int c = cnt[node];
    unsigned int s = cur_end[node] - c;
    const uint2* h2 = (const uint2*)hs;

    uint2 u0 = h2[(size_t)node * 32 + l];  // self-loop term
    float4 acc = make_float4(bitf(u0.x << 16), bitf(u0.x & 0xffff0000u),
                             bitf(u0.y << 16), bitf(u0.y & 0xffff0000u));

    for (unsigned int base = 0; base < c; base += 32) {
        int m = min(32u, c - base);
        int v = (base + (unsigned)l < c) ? sorted_src[s + base + l] : 0;
        for (int j = 0; j < m; ++j) {
            int src = __shfl(v, j, 32);
            uint2 u = h2[(size_t)src * 32 + l];
            acc.x += bitf(u.x << 16);
            acc.y += bitf(u.x & 0xffff0000u);
            acc.z += bitf(u.y << 16);
            acc.w += bitf(u.y & 0xffff0000u);
        }
    }

    float dd = dis[node];
    float4 bv = ((const float4*)b)[l];
    ((float4*)out)[(size_t)node * 32 + l] =
        make_float4(acc.x * dd + bv.x, acc.y * dd + bv.y, acc.z * dd + bv.z, acc.w * dd + bv.w);
}

extern "C" void kernel_launch(void* const* d_in, const int* in_sizes, int n_in,
                              void* d_out, int out_size, void* d_ws, size_t ws_size,
                              hipStream_t stream) {
    const float* x = (const float*)d_in[0];
    const int* ei = (const int*)d_in[1];  // [2, E] int32
    const float* W = (const float*)d_in[2];
    const float* b = (const float*)d_in[3];
    float* out = (float*)d_out;

    int n = in_sizes[0] / D;  // 50000
    int E = in_sizes[1] / 2;  // 600000
    int nb = (n + SCAN_CHUNK - 1) / SCAN_CHUNK;  // 49

    unsigned int* cnt = (unsigned int*)d_ws;
    unsigned int* cursor = cnt + n;
    float* dis = (float*)(cursor + n);
    unsigned int* bsum = (unsigned int*)(dis + n);
    int* sorted_src = (int*)(bsum + 64);
    unsigned short* xb = (unsigned short*)(sorted_src + E);
    unsigned short* hs = xb + (size_t)n * D;
    unsigned short* wt = hs + (size_t)n * D;

    hipMemsetAsync(cnt, 0, n * sizeof(unsigned int), stream);
    cast_kernel<<<1024, 256, 0, stream>>>(x, xb, n * (D / 4));
    wt_kernel<<<64, 256, 0, stream>>>(W, wt);
    deg_kernel<<<(E + 255) / 256, 256, 0, stream>>>(ei + E, cnt, E);
    reduce_kernel<<<nb, 256, 0, stream>>>(cnt, bsum, n);
    bscan_kernel<<<1, 64, 0, stream>>>(bsum, nb);
    scanwrite_kernel<<<nb, 256, 0, stream>>>(cnt, bsum, cursor, dis, n);
    place_kernel<<<(E + 255) / 256, 256, 0, stream>>>(ei, cursor, sorted_src, E);
    mfma_gemm<<<(n + 63) / 64, 256, 0, stream>>>(xb, wt, dis, hs, n);
    gather_kernel<<<(n * 32 + 255) / 256, 256, 0, stream>>>(sorted_src, cursor, cnt, dis, hs, b,
                                                            out, n);
}

// Round 5
// 129.095 us; speedup vs baseline: 4.4402x; 1.0503x over previous
//
#include <hip/hip_runtime.h>

#define D 128
#define SCAN_CHUNK 1024

typedef __bf16 bf16x8 __attribute__((ext_vector_type(8)));
typedef float f32x4 __attribute__((ext_vector_type(4)));

static __device__ __forceinline__ unsigned short f2bf(float x) {
    unsigned int u = __builtin_bit_cast(unsigned int, x);
    unsigned int r = u + 0x7fffu + ((u >> 16) & 1u);
    return (unsigned short)(r >> 16);
}
static __device__ __forceinline__ float bitf(unsigned int u) {
    return __builtin_bit_cast(float, u);
}

// ---------------- prep: zero cnt + cast X->bf16 + transpose W->bf16 ----------------
__global__ __launch_bounds__(256) void prep_kernel(const float* __restrict__ x,
                                                   const float* __restrict__ W,
                                                   unsigned int* __restrict__ cnt,
                                                   unsigned short* __restrict__ xb,
                                                   unsigned short* __restrict__ wt, int n) {
    int tid = blockIdx.x * 256 + threadIdx.x;
    int stride = gridDim.x * 256;
    // zero cnt (n divisible by 4)
    int nz = n >> 2;
    for (int i = tid; i < nz; i += stride) ((uint4*)cnt)[i] = make_uint4(0u, 0u, 0u, 0u);
    // cast X (n*128 elems = n*32 float4s)
    int nx = n * 32;
    for (int i = tid; i < nx; i += stride) {
        float4 v = ((const float4*)x)[i];
        ushort4 o;
        o.x = f2bf(v.x); o.y = f2bf(v.y); o.z = f2bf(v.z); o.w = f2bf(v.w);
        ((ushort4*)xb)[i] = o;
    }
    // Wt[nc][k] = bf16(W[k][nc])
    for (int i = tid; i < D * D; i += stride) {
        int r = i >> 7, c = i & 127;
        wt[c * 128 + r] = f2bf(W[i]);
    }
}

// ---------------- degree ----------------
__global__ __launch_bounds__(256) void deg_kernel(const int* __restrict__ ei_dst,
                                                  unsigned int* __restrict__ cnt, int E) {
    int e = blockIdx.x * 256 + threadIdx.x;
    if (e < E) atomicAdd(&cnt[ei_dst[e]], 1u);
}

// ---------------- scan phase 1: per-block reduce ----------------
__global__ __launch_bounds__(256) void reduce_kernel(const unsigned int* __restrict__ cnt,
                                                     unsigned int* __restrict__ bsum, int n) {
    int t = threadIdx.x;
    int i0 = blockIdx.x * SCAN_CHUNK + t * 4;
    unsigned int s = 0;
    if (i0 + 3 < n) {
        uint4 v = *(const uint4*)&cnt[i0];
        s = v.x + v.y + v.z + v.w;
    } else {
        for (int i = i0; i < n && i < i0 + 4; ++i) s += cnt[i];
    }
#pragma unroll
    for (int d = 32; d; d >>= 1) s += __shfl_down(s, d);
    __shared__ unsigned int ws_[4];
    int wid = t >> 6, lane = t & 63;
    if (lane == 0) ws_[wid] = s;
    __syncthreads();
    if (t == 0) bsum[blockIdx.x] = ws_[0] + ws_[1] + ws_[2] + ws_[3];
}

// ---------------- scan phase 2 ----------------
__global__ __launch_bounds__(64) void bscan_kernel(unsigned int* __restrict__ bsum, int nb) {
    int lane = threadIdx.x;
    unsigned int v = (lane < nb) ? bsum[lane] : 0u;
    unsigned int s = v;
#pragma unroll
    for (int d = 1; d < 64; d <<= 1) {
        unsigned int u = __shfl_up(s, d);
        if (lane >= d) s += u;
    }
    if (lane < nb) bsum[lane] = s - v;
}

// ---------------- scan phase 3: writeback cursor (start offsets) + dis ----------------
__global__ __launch_bounds__(256) void scanwrite_kernel(const unsigned int* __restrict__ cnt,
                                                        const unsigned int* __restrict__ bsum,
                                                        unsigned int* __restrict__ cursor,
                                                        float* __restrict__ dis, int n) {
    int t = threadIdx.x;
    int i0 = blockIdx.x * SCAN_CHUNK + t * 4;
    unsigned int v0 = 0, v1 = 0, v2 = 0, v3 = 0;
    if (i0 + 3 < n) {
        uint4 v = *(const uint4*)&cnt[i0];
        v0 = v.x; v1 = v.y; v2 = v.z; v3 = v.w;
    } else if (i0 < n) {
        v0 = cnt[i0];
        if (i0 + 1 < n) v1 = cnt[i0 + 1];
        if (i0 + 2 < n) v2 = cnt[i0 + 2];
    }
    unsigned int tot = v0 + v1 + v2 + v3;
    unsigned int s = tot;
    int lane = t & 63, wid = t >> 6;
#pragma unroll
    for (int d = 1; d < 64; d <<= 1) {
        unsigned int u = __shfl_up(s, d);
        if (lane >= d) s += u;
    }
    __shared__ unsigned int wsum[4];
    if (lane == 63) wsum[wid] = s;
    __syncthreads();
    unsigned int base = bsum[blockIdx.x];
    for (int w = 0; w < wid; ++w) base += wsum[w];
    unsigned int tb = base + s - tot;
    unsigned int o0 = tb, o1 = tb + v0, o2 = o1 + v1, o3 = o2 + v2;
    if (i0 + 3 < n) {
        *(uint4*)&cursor[i0] = make_uint4(o0, o1, o2, o3);
        *(float4*)&dis[i0] = make_float4(rsqrtf((float)v0 + 1.0f), rsqrtf((float)v1 + 1.0f),
                                         rsqrtf((float)v2 + 1.0f), rsqrtf((float)v3 + 1.0f));
    } else if (i0 < n) {
        cursor[i0] = o0; dis[i0] = rsqrtf((float)v0 + 1.0f);
        if (i0 + 1 < n) { cursor[i0 + 1] = o1; dis[i0 + 1] = rsqrtf((float)v1 + 1.0f); }
        if (i0 + 2 < n) { cursor[i0 + 2] = o2; dis[i0 + 2] = rsqrtf((float)v2 + 1.0f); }
    }
}

// ---------------- place edges into dst-sorted order ----------------
__global__ __launch_bounds__(256) void place_kernel(const int* __restrict__ ei,
                                                    unsigned int* __restrict__ cursor,
                                                    int* __restrict__ sorted_src, int E) {
    int e = blockIdx.x * 256 + threadIdx.x;
    if (e < E) {
        int src = ei[e];
        int dst = ei[E + e];
        unsigned int p = atomicAdd(&cursor[dst], 1u);
        sorted_src[p] = src;
    }
}

// ---------------- MFMA gemm: hs = bf16((Xb*W) * dis[row]) ----------------
__global__ __launch_bounds__(256) void mfma_gemm(const unsigned short* __restrict__ xb,
                                                 const unsigned short* __restrict__ wt,
                                                 const float* __restrict__ dis,
                                                 unsigned short* __restrict__ hs, int n) {
    __shared__ uint4 Xs[64 * 16];   // 16 KB
    __shared__ uint4 Ws[128 * 16];  // 32 KB
    int t = threadIdx.x;
    int rowbase = blockIdx.x * 64;

    const uint4* wg = (const uint4*)wt;
#pragma unroll
    for (int j = 0; j < 8; ++j) {
        int gi = t + j * 256;
        int r = gi >> 4, s = gi & 15;
        Ws[r * 16 + (s ^ (r & 7))] = wg[gi];
    }
    const uint4* xg = (const uint4*)xb;
#pragma unroll
    for (int j = 0; j < 4; ++j) {
        int gi = t + j * 256;
        int r = gi >> 4, s = gi & 15;
        uint4 v = make_uint4(0u, 0u, 0u, 0u);
        if (rowbase + r < n) v = xg[(size_t)rowbase * 16 + gi];
        Xs[r * 16 + (s ^ (r & 7))] = v;
    }
    __syncthreads();

    int w = t >> 6, l = t & 63;
    int lr = l & 15, lg = l >> 4;
    f32x4 acc[4][2] = {};

#pragma unroll
    for (int kt = 0; kt < 4; ++kt) {
        int ks = kt * 4 + lg;
        bf16x8 bfr[2];
#pragma unroll
        for (int ct = 0; ct < 2; ++ct) {
            int nc = w * 32 + ct * 16 + lr;
            bfr[ct] = __builtin_bit_cast(bf16x8, Ws[nc * 16 + (ks ^ (nc & 7))]);
        }
#pragma unroll
        for (int mt = 0; mt < 4; ++mt) {
            int mr = mt * 16 + lr;
            bf16x8 afr = __builtin_bit_cast(bf16x8, Xs[mr * 16 + (ks ^ (mr & 7))]);
            acc[mt][0] = __builtin_amdgcn_mfma_f32_16x16x32_bf16(afr, bfr[0], acc[mt][0], 0, 0, 0);
            acc[mt][1] = __builtin_amdgcn_mfma_f32_16x16x32_bf16(afr, bfr[1], acc[mt][1], 0, 0, 0);
        }
    }

#pragma unroll
    for (int mt = 0; mt < 4; ++mt) {
        int row0 = rowbase + mt * 16 + lg * 4;
#pragma unroll
        for (int r = 0; r < 4; ++r) {
            int grow = row0 + r;
            if (grow < n) {
                float dv = dis[grow];
#pragma unroll
                for (int ct = 0; ct < 2; ++ct) {
                    int col = w * 32 + ct * 16 + lr;
                    hs[(size_t)grow * 128 + col] = f2bf(acc[mt][ct][r] * dv);
                }
            }
        }
    }
}

// ---------------- gather: out[dst] = dis[dst]*(hs[dst] + sum hs[src]) + b ----------------
__global__ __launch_bounds__(256) void gather_kernel(const int* __restrict__ sorted_src,
                                                     const unsigned int* __restrict__ cur_end,
                                                     const unsigned int* __restrict__ cnt,
                                                     const float* __restrict__ dis,
                                                     const unsigned short* __restrict__ hs,
                                                     const float* __restrict__ b,
                                                     float* __restrict__ out, int n) {
    int node = (blockIdx.x * 256 + threadIdx.x) >> 5;
    int l = threadIdx.x & 31;
    if (node >= n) return;
    unsigned int c = cnt[node];
    unsigned int s = cur_end[node] - c;
    const uint2* h2 = (const uint2*)hs;

    uint2 u0 = h2[(size_t)node * 32 + l];  // self-loop term
    float4 acc = make_float4(bitf(u0.x << 16), bitf(u0.x & 0xffff0000u),
                             bitf(u0.y << 16), bitf(u0.y & 0xffff0000u));

    for (unsigned int base = 0; base < c; base += 32) {
        int m = min(32u, c - base);
        int v = (base + (unsigned)l < c) ? sorted_src[s + base + l] : 0;
        for (int j = 0; j < m; ++j) {
            int src = __shfl(v, j, 32);
            uint2 u = h2[(size_t)src * 32 + l];
            acc.x += bitf(u.x << 16);
            acc.y += bitf(u.x & 0xffff0000u);
            acc.z += bitf(u.y << 16);
            acc.w += bitf(u.y & 0xffff0000u);
        }
    }

    float dd = dis[node];
    float4 bv = ((const float4*)b)[l];
    ((float4*)out)[(size_t)node * 32 + l] =
        make_float4(acc.x * dd + bv.x, acc.y * dd + bv.y, acc.z * dd + bv.z, acc.w * dd + bv.w);
}

extern "C" void kernel_launch(void* const* d_in, const int* in_sizes, int n_in,
                              void* d_out, int out_size, void* d_ws, size_t ws_size,
                              hipStream_t stream) {
    const float* x = (const float*)d_in[0];
    const int* ei = (const int*)d_in[1];  // [2, E] int32
    const float* W = (const float*)d_in[2];
    const float* b = (const float*)d_in[3];
    float* out = (float*)d_out;

    int n = in_sizes[0] / D;  // 50000
    int E = in_sizes[1] / 2;  // 600000
    int nb = (n + SCAN_CHUNK - 1) / SCAN_CHUNK;  // 49

    unsigned int* cnt = (unsigned int*)d_ws;
    unsigned int* cursor = cnt + n;
    float* dis = (float*)(cursor + n);
    unsigned int* bsum = (unsigned int*)(dis + n);
    int* sorted_src = (int*)(bsum + 64);
    unsigned short* xb = (unsigned short*)(sorted_src + E);
    unsigned short* hs = xb + (size_t)n * D;
    unsigned short* wt = hs + (size_t)n * D;

    prep_kernel<<<1024, 256, 0, stream>>>(x, W, cnt, xb, wt, n);
    deg_kernel<<<(E + 255) / 256, 256, 0, stream>>>(ei + E, cnt, E);
    reduce_kernel<<<nb, 256, 0, stream>>>(cnt, bsum, n);
    bscan_kernel<<<1, 64, 0, stream>>>(bsum, nb);
    scanwrite_kernel<<<nb, 256, 0, stream>>>(cnt, bsum, cursor, dis, n);
    place_kernel<<<(E + 255) / 256, 256, 0, stream>>>(ei, cursor, sorted_src, E);
    mfma_gemm<<<(n + 63) / 64, 256, 0, stream>>>(xb, wt, dis, hs, n);
    gather_kernel<<<(n * 32 + 255) / 256, 256, 0, stream>>>(sorted_src, cursor, cnt, dis, hs, b,
                                                            out, n);
}